// Round 1
// baseline (514.334 us; speedup 1.0000x reference)
//
#include <hip/hip_runtime.h>

#define BATCH 16384
#define DIM   4096

typedef __bf16 bf16x8 __attribute__((ext_vector_type(8)));
typedef float  f32x4  __attribute__((ext_vector_type(4)));
typedef unsigned short u16x8 __attribute__((ext_vector_type(8)));
typedef unsigned short u16x4 __attribute__((ext_vector_type(4)));

// ---- workspace layout (float offsets) ----
#define WS_ROWSUM 0         // 16384
#define WS_MED    16384     // 1
#define WS_NPART  16400     // 256*2
#define WS_SIG2   16928     // 1
#define WS_CSUM   17024     // 64
#define WS_CSQ    17088     // 64
#define WS_SC2    17152     // 32
#define WS_CC2    17184     // 32
#define WS_SC3    17216     // 64
#define WS_CC3    17280     // 64
#define WS_A2PART 17408     // 256*64
#define WS_A3PART 34816     // 256*128
#define WS_R      131072    // 16384*64 fp32
#define WS_A2     1179648   // 16384*32 fp32
#define WS_A3     1703936   // 16384*64 fp32
#define WS_WTIN   2752512   // 64*4096 bf16 (as ushort)
#define WS_WTO    2883584   // 3 * 4096*64 bf16

__device__ __forceinline__ unsigned short f2bf(float f){
  union { float f; unsigned u; } v; v.f = f;
  unsigned r = v.u + 0x7FFFu + ((v.u >> 16) & 1u);
  return (unsigned short)(r >> 16);
}

// L0: convert/transpose weights to bf16.
// wtin[n][k] = bf16(W_in[k][n])  (64 x 4096)
// wto[m][n][k] = bf16(W_m[k][n]) (3 x 4096 x 64)
__global__ void k_prep(const float* __restrict__ Win, const float* __restrict__ Wpi,
                       const float* __restrict__ Wm,  const float* __restrict__ Wth,
                       float* __restrict__ ws){
  unsigned short* wtin = (unsigned short*)(ws + WS_WTIN);
  unsigned short* wto  = (unsigned short*)(ws + WS_WTO);
  int idx = blockIdx.x * 256 + threadIdx.x;
  if (idx < 262144) {
    int k = idx >> 6, n = idx & 63;          // read coalesced
    wtin[n * 4096 + k] = f2bf(Win[idx]);
  } else {
    int r = idx - 262144;
    int m = r >> 18, rr = r & 262143;
    int k = rr >> 12, n = rr & 4095;         // rr = k*4096 + n, read coalesced
    const float* W = (m == 0) ? Wpi : ((m == 1) ? Wm : Wth);
    wto[m * 262144 + n * 64 + k] = f2bf(W[rr]);
  }
}

// L1: row sums of x. one wave per row.
__global__ void k_rowsum(const float* __restrict__ x, float* __restrict__ ws){
  int w = threadIdx.x >> 6, lane = threadIdx.x & 63;
  int row = blockIdx.x * 4 + w;
  const float4* xr = (const float4*)(x + (size_t)row * DIM);
  float s = 0.f;
  #pragma unroll
  for (int i = 0; i < 16; ++i) {
    float4 v = xr[lane + 64 * i];
    s += (v.x + v.y) + (v.z + v.w);
  }
  #pragma unroll
  for (int m = 32; m; m >>= 1) s += __shfl_xor(s, m);
  if (lane == 0) ws[WS_ROWSUM + row] = s;
}

// L2: lower median of the 16384 row sums via counting selection.
// grid 256, block 256: block b tests candidates b*64..b*64+63; 4 waves split the scan range.
__global__ void k_median(float* __restrict__ ws){
  __shared__ int cls[4][64], ces[4][64];
  const float* rs = ws + WS_ROWSUM;
  int t = threadIdx.x, lane = t & 63, q = t >> 6;
  float cand = rs[blockIdx.x * 64 + lane];
  int cl = 0, ce = 0;
  const float* base = rs + q * 4096;
  for (int i = 0; i < 4096; ++i) {           // wave-uniform address -> scalar loads
    float v = base[i];
    cl += (v < cand);
    ce += (v == cand);
  }
  cls[q][lane] = cl; ces[q][lane] = ce;
  __syncthreads();
  if (t < 64) {
    int C = cls[0][t] + cls[1][t] + cls[2][t] + cls[3][t];
    int E = ces[0][t] + ces[1][t] + ces[2][t] + ces[3][t];
    if (C <= 8191 && 8191 < C + E) ws[WS_MED] = cand;
  }
}

// L3: fused norm + GEMM pass.
//   norm[i][k] = log(x[i][k] * (med/rowsum_i) + 1)
//   R = norm @ W_in (fp32 accum via bf16 MFMA), plus global sum/sumsq of norm.
// grid 256 (64 rows each), block 512 (8 waves: 4 row-groups x 2 col-halves).
__global__ __launch_bounds__(512) void k_passB(const float* __restrict__ x, float* __restrict__ ws){
  __shared__ __align__(16) char Ab[2 * 8192];   // [2][64 rows][64 k] bf16, XOR-swizzled 16B chunks
  __shared__ __align__(16) char Bb[2 * 8192];   // [2][64 n   ][64 k] bf16, XOR-swizzled
  __shared__ float ainv_s[64];
  __shared__ float red[8][2];

  const unsigned short* wtin = (const unsigned short*)(ws + WS_WTIN);
  int tid = threadIdx.x;
  int r0 = blockIdx.x * 64;
  float med = ws[WS_MED];
  if (tid < 64) ainv_s[tid] = med / ws[WS_ROWSUM + r0 + tid];
  __syncthreads();

  int w = tid >> 6, lane = tid & 63;
  int li = lane & 15, u = lane >> 4;
  int wr = (w & 3) * 16;        // wave row base within tile
  int wc = (w >> 2) * 32;       // wave col base

  // staging roles
  int xrow0 = tid >> 4;               // 0..31 (and +32)
  int xcol0 = (tid & 15) * 4;         // 0..60
  int wn = tid >> 3, wkc = tid & 7;   // Bt: row n, 16B chunk

  float a0 = ainv_s[xrow0], a1 = ainv_s[xrow0 + 32];

  f32x4 acc[2];
  #pragma unroll
  for (int c = 0; c < 2; ++c) acc[c] = (f32x4){0.f, 0.f, 0.f, 0.f};
  float nsum = 0.f, nsq = 0.f;

  float4 xa, xb; u16x8 wv;
  auto LOADT = [&](int t){
    int coff = t * 64;
    xa = *(const float4*)(x + (size_t)(r0 + xrow0) * DIM + coff + xcol0);
    xb = *(const float4*)(x + (size_t)(r0 + xrow0 + 32) * DIM + coff + xcol0);
    wv = *(const u16x8*)(wtin + (size_t)wn * DIM + coff + wkc * 8);
  };
  auto WRITET = [&](int buf){
    float n0 = __logf(fmaf(xa.x, a0, 1.f));
    float n1 = __logf(fmaf(xa.y, a0, 1.f));
    float n2 = __logf(fmaf(xa.z, a0, 1.f));
    float n3 = __logf(fmaf(xa.w, a0, 1.f));
    float n4 = __logf(fmaf(xb.x, a1, 1.f));
    float n5 = __logf(fmaf(xb.y, a1, 1.f));
    float n6 = __logf(fmaf(xb.z, a1, 1.f));
    float n7 = __logf(fmaf(xb.w, a1, 1.f));
    nsum += ((n0 + n1) + (n2 + n3)) + ((n4 + n5) + (n6 + n7));
    nsq  += ((n0*n0 + n1*n1) + (n2*n2 + n3*n3)) + ((n4*n4 + n5*n5) + (n6*n6 + n7*n7));
    u16x4 p0 = { f2bf(n0), f2bf(n1), f2bf(n2), f2bf(n3) };
    u16x4 p1 = { f2bf(n4), f2bf(n5), f2bf(n6), f2bf(n7) };
    int c = xcol0 >> 3, sub = (xcol0 >> 2) & 1;
    int row1 = xrow0 + 32;
    *(u16x4*)(Ab + buf * 8192 + xrow0 * 128 + ((c ^ (xrow0 & 7)) << 4) + sub * 8) = p0;
    *(u16x4*)(Ab + buf * 8192 + row1  * 128 + ((c ^ (row1  & 7)) << 4) + sub * 8) = p1;
    *(u16x8*)(Bb + buf * 8192 + wn * 128 + ((wkc ^ (wn & 7)) << 4)) = wv;
  };

  LOADT(0);
  WRITET(0);
  __syncthreads();
  int cur = 0;
  int arow = wr + li;
  for (int t = 0; t < 64; ++t) {
    if (t < 63) LOADT(t + 1);
    const char* Au = Ab + cur * 8192;
    const char* Bu = Bb + cur * 8192;
    #pragma unroll
    for (int kk = 0; kk < 2; ++kk) {
      bf16x8 aF = *(const bf16x8*)(Au + arow * 128 + (((kk * 4 + u) ^ (arow & 7)) << 4));
      #pragma unroll
      for (int cg = 0; cg < 2; ++cg) {
        int n = wc + cg * 16 + li;
        bf16x8 bF = *(const bf16x8*)(Bu + n * 128 + (((kk * 4 + u) ^ (n & 7)) << 4));
        acc[cg] = __builtin_amdgcn_mfma_f32_16x16x32_bf16(aF, bF, acc[cg], 0, 0, 0);
      }
    }
    __syncthreads();
    if (t < 63) WRITET(cur ^ 1);
    __syncthreads();
    cur ^= 1;
  }

  // store R
  float* R = ws + WS_R;
  #pragma unroll
  for (int cg = 0; cg < 2; ++cg) {
    #pragma unroll
    for (int r = 0; r < 4; ++r) {
      int row = r0 + wr + u * 4 + r;
      int col = wc + cg * 16 + li;
      R[row * 64 + col] = acc[cg][r];
    }
  }
  // reduce norm stats
  #pragma unroll
  for (int m = 32; m; m >>= 1) { nsum += __shfl_xor(nsum, m); nsq += __shfl_xor(nsq, m); }
  if (lane == 0) { red[w][0] = nsum; red[w][1] = nsq; }
  __syncthreads();
  if (tid == 0) {
    float S = 0.f, Q = 0.f;
    for (int i = 0; i < 8; ++i) { S += red[i][0]; Q += red[i][1]; }
    ws[WS_NPART + blockIdx.x * 2]     = S;
    ws[WS_NPART + blockIdx.x * 2 + 1] = Q;
  }
}

// L4: column stats of R (blocks 0..63) and sigma^2 of norm (block 64).
__global__ void k_stats(float* __restrict__ ws){
  __shared__ float rbuf[4][2];
  int t = threadIdx.x, lane = t & 63, w = t >> 6;
  float s = 0.f, q = 0.f;
  if (blockIdx.x < 64) {
    int j = blockIdx.x;
    const float* R = ws + WS_R;
    for (int i = t; i < 16384; i += 256) { float v = R[i * 64 + j]; s += v; q += v * v; }
  } else {
    s = ws[WS_NPART + t * 2];
    q = ws[WS_NPART + t * 2 + 1];
  }
  #pragma unroll
  for (int m = 32; m; m >>= 1) { s += __shfl_xor(s, m); q += __shfl_xor(q, m); }
  if (lane == 0) { rbuf[w][0] = s; rbuf[w][1] = q; }
  __syncthreads();
  if (t == 0) {
    float S = rbuf[0][0] + rbuf[1][0] + rbuf[2][0] + rbuf[3][0];
    float Q = rbuf[0][1] + rbuf[1][1] + rbuf[2][1] + rbuf[3][1];
    if (blockIdx.x < 64) {
      ws[WS_CSUM + blockIdx.x] = S;
      ws[WS_CSQ  + blockIdx.x] = Q;
    } else {
      double N = 67108864.0;
      double var = ((double)Q - (double)S * (double)S / N) / (N - 1.0);
      ws[WS_SIG2] = (float)var;
    }
  }
}

// L5: h1 = relu(BN1 applied to R), a2 = h1 @ W_enc + b_enc, plus column partials of a2.
__global__ void k_layer1(const float* __restrict__ g1, const float* __restrict__ bt1,
                         const float* __restrict__ Wenc, const float* __restrict__ benc,
                         float* __restrict__ ws){
  __shared__ float sc1[64], cc1[64];
  __shared__ float h1[64][65];
  __shared__ float we[64][33];
  int t = threadIdx.x;
  if (t < 64) {
    float sig2 = ws[WS_SIG2];
    float cm = ws[WS_CSUM + t] * (1.f / 16384.f);
    float cv = ws[WS_CSQ  + t] * (1.f / 16384.f) - cm * cm;
    float sc = g1[t] * rsqrtf(cv + sig2 * 1e-5f);
    sc1[t] = sc; cc1[t] = bt1[t] - cm * sc;
  }
  for (int i = t; i < 2048; i += 256) we[i >> 5][i & 31] = Wenc[i];
  __syncthreads();
  int r0 = blockIdx.x * 64;
  const float* R = ws + WS_R;
  for (int i = t; i < 4096; i += 256) {
    int row = i >> 6, col = i & 63;
    float v = fmaf(R[(r0 + row) * 64 + col], sc1[col], cc1[col]);
    h1[row][col] = fmaxf(v, 0.f);
  }
  __syncthreads();
  int row = t & 63, cb = t >> 6;
  float a[8];
  #pragma unroll
  for (int j = 0; j < 8; ++j) a[j] = benc[cb * 8 + j];
  for (int k = 0; k < 64; ++k) {
    float hv = h1[row][k];
    #pragma unroll
    for (int j = 0; j < 8; ++j) a[j] = fmaf(hv, we[k][cb * 8 + j], a[j]);
  }
  float* A2 = ws + WS_A2;
  #pragma unroll
  for (int j = 0; j < 8; ++j) A2[(r0 + row) * 32 + cb * 8 + j] = a[j];
  int lane = t & 63;
  #pragma unroll
  for (int j = 0; j < 8; ++j) {
    float s = a[j], q = a[j] * a[j];
    #pragma unroll
    for (int m = 32; m; m >>= 1) { s += __shfl_xor(s, m); q += __shfl_xor(q, m); }
    if (lane == 0) {
      int c = cb * 8 + j;
      ws[WS_A2PART + blockIdx.x * 64 + c * 2]     = s;
      ws[WS_A2PART + blockIdx.x * 64 + c * 2 + 1] = q;
    }
  }
}

// L6: reduce a2 partials -> BN2 scale/shift.
__global__ void k_red2(const float* __restrict__ g2, const float* __restrict__ bt2, float* __restrict__ ws){
  __shared__ float red[64];
  int t = threadIdx.x;
  if (t < 64) {
    float s = 0.f;
    for (int b = 0; b < 256; ++b) s += ws[WS_A2PART + b * 64 + t];
    red[t] = s;
  }
  __syncthreads();
  if (t < 32) {
    float S = red[2 * t], Q = red[2 * t + 1];
    float cm = S * (1.f / 16384.f);
    float cv = Q * (1.f / 16384.f) - cm * cm;
    float sc = g2[t] * rsqrtf(cv + 1e-5f);
    ws[WS_SC2 + t] = sc; ws[WS_CC2 + t] = bt2[t] - cm * sc;
  }
}

// L7: h2 = relu(BN2(a2)), a3 = h2 @ W_dec + b_dec, plus column partials of a3.
__global__ void k_layer2(const float* __restrict__ Wdec, const float* __restrict__ bdec,
                         float* __restrict__ ws){
  __shared__ float h2[64][33];
  __shared__ float wd[32][65];
  __shared__ float sc2[32], cc2[32];
  int t = threadIdx.x;
  if (t < 32) { sc2[t] = ws[WS_SC2 + t]; cc2[t] = ws[WS_CC2 + t]; }
  for (int i = t; i < 2048; i += 256) wd[i >> 6][i & 63] = Wdec[i];
  __syncthreads();
  int r0 = blockIdx.x * 64;
  const float* A2 = ws + WS_A2;
  for (int i = t; i < 2048; i += 256) {
    int row = i >> 5, col = i & 31;
    float v = fmaf(A2[(r0 + row) * 32 + col], sc2[col], cc2[col]);
    h2[row][col] = fmaxf(v, 0.f);
  }
  __syncthreads();
  int row = t & 63, cb = t >> 6;
  float a[16];
  #pragma unroll
  for (int j = 0; j < 16; ++j) a[j] = bdec[cb * 16 + j];
  for (int k = 0; k < 32; ++k) {
    float hv = h2[row][k];
    #pragma unroll
    for (int j = 0; j < 16; ++j) a[j] = fmaf(hv, wd[k][cb * 16 + j], a[j]);
  }
  float* A3 = ws + WS_A3;
  #pragma unroll
  for (int j = 0; j < 16; ++j) A3[(r0 + row) * 64 + cb * 16 + j] = a[j];
  int lane = t & 63;
  #pragma unroll
  for (int j = 0; j < 16; ++j) {
    float s = a[j], q = a[j] * a[j];
    #pragma unroll
    for (int m = 32; m; m >>= 1) { s += __shfl_xor(s, m); q += __shfl_xor(q, m); }
    if (lane == 0) {
      int c = cb * 16 + j;
      ws[WS_A3PART + blockIdx.x * 128 + c * 2]     = s;
      ws[WS_A3PART + blockIdx.x * 128 + c * 2 + 1] = q;
    }
  }
}

// L8: reduce a3 partials -> BN3 scale/shift.
__global__ void k_red3(const float* __restrict__ g3, const float* __restrict__ bt3, float* __restrict__ ws){
  __shared__ float red[128];
  int t = threadIdx.x;
  if (t < 128) {
    float s = 0.f;
    for (int b = 0; b < 256; ++b) s += ws[WS_A3PART + b * 128 + t];
    red[t] = s;
  }
  __syncthreads();
  if (t < 64) {
    float S = red[2 * t], Q = red[2 * t + 1];
    float cm = S * (1.f / 16384.f);
    float cv = Q * (1.f / 16384.f) - cm * cm;
    float sc = g3[t] * rsqrtf(cv + 1e-5f);
    ws[WS_SC3 + t] = sc; ws[WS_CC3 + t] = bt3[t] - cm * sc;
  }
}

// L9: heads. h3 = relu(BN3(a3)) computed in-register; out = act(h3 @ W + b).
// grid 4096 = 256 row-blocks x 16 col-blocks; block 256 (4 waves x 16 rows).
__global__ __launch_bounds__(256) void k_out(const float* __restrict__ bpi, const float* __restrict__ bm,
                      const float* __restrict__ bth, float* __restrict__ out,
                      float* __restrict__ ws){
  __shared__ __align__(16) char WB[256 * 128];   // [256 n][64 k] bf16, XOR-swizzled
  int t = threadIdx.x;
  int bx = blockIdx.x;
  int rb = bx >> 4, cb = bx & 15;
  int r0 = rb * 64, c0 = cb * 256;
  int w = t >> 6, lane = t & 63;
  int u = lane >> 4, li = lane & 15;

  const float* A3 = ws + WS_A3;
  const float* SC = ws + WS_SC3;
  const float* CC = ws + WS_CC3;
  int arow = r0 + w * 16 + li;
  bf16x8 aF[2];
  #pragma unroll
  for (int h = 0; h < 2; ++h) {
    u16x8 uu;
    #pragma unroll
    for (int e = 0; e < 8; ++e) {
      int k = h * 32 + u * 8 + e;
      float hv = fmaxf(fmaf(A3[arow * 64 + k], SC[k], CC[k]), 0.f);
      uu[e] = f2bf(hv);
    }
    aF[h] = __builtin_bit_cast(bf16x8, uu);
  }

  const unsigned short* wto = (const unsigned short*)(ws + WS_WTO);
  for (int m = 0; m < 3; ++m) {
    __syncthreads();
    const unsigned short* src = wto + (size_t)m * 262144 + (size_t)c0 * 64;
    for (int ch = t; ch < 2048; ch += 256) {   // 2048 16B chunks
      int n = ch >> 3, kc = ch & 7;
      u16x8 vchunk = *(const u16x8*)(src + n * 64 + kc * 8);
      *(u16x8*)(WB + n * 128 + ((kc ^ (n & 7)) << 4)) = vchunk;
    }
    __syncthreads();
    const float* bias = (m == 0) ? bpi : ((m == 1) ? bm : bth);
    float* po = out + (size_t)m * 67108864;
    for (int cg = 0; cg < 16; ++cg) {
      int n = cg * 16 + li;
      bf16x8 bF0 = *(const bf16x8*)(WB + n * 128 + (((0 + u) ^ (n & 7)) << 4));
      bf16x8 bF1 = *(const bf16x8*)(WB + n * 128 + (((4 + u) ^ (n & 7)) << 4));
      f32x4 d = (f32x4){0.f, 0.f, 0.f, 0.f};
      d = __builtin_amdgcn_mfma_f32_16x16x32_bf16(aF[0], bF0, d, 0, 0, 0);
      d = __builtin_amdgcn_mfma_f32_16x16x32_bf16(aF[1], bF1, d, 0, 0, 0);
      int col = c0 + cg * 16 + li;
      float bv = bias[col];
      #pragma unroll
      for (int r = 0; r < 4; ++r) {
        int row = r0 + w * 16 + u * 4 + r;
        float z = d[r] + bv;
        float res = (m == 0) ? (1.f / (1.f + __expf(-z))) : __expf(z);
        po[(size_t)row * 4096 + col] = res;
      }
    }
  }
}

extern "C" void kernel_launch(void* const* d_in, const int* in_sizes, int n_in,
                              void* d_out, int out_size, void* d_ws, size_t ws_size,
                              hipStream_t stream) {
  const float* x    = (const float*)d_in[0];
  const float* Win  = (const float*)d_in[1];
  // d_in[2] = b_in: cancels through BN1, unused.
  const float* g1   = (const float*)d_in[3];
  const float* bt1  = (const float*)d_in[4];
  const float* Wenc = (const float*)d_in[5];
  const float* benc = (const float*)d_in[6];
  const float* g2   = (const float*)d_in[7];
  const float* bt2  = (const float*)d_in[8];
  const float* Wdec = (const float*)d_in[9];
  const float* bdec = (const float*)d_in[10];
  const float* g3   = (const float*)d_in[11];
  const float* bt3  = (const float*)d_in[12];
  const float* Wpi  = (const float*)d_in[13];
  const float* bpi  = (const float*)d_in[14];
  const float* Wm   = (const float*)d_in[15];
  const float* bm   = (const float*)d_in[16];
  const float* Wth  = (const float*)d_in[17];
  const float* bth  = (const float*)d_in[18];
  float* ws  = (float*)d_ws;
  float* out = (float*)d_out;

  hipLaunchKernelGGL(k_prep,   dim3(4096), dim3(256), 0, stream, Win, Wpi, Wm, Wth, ws);
  hipLaunchKernelGGL(k_rowsum, dim3(4096), dim3(256), 0, stream, x, ws);
  hipLaunchKernelGGL(k_median, dim3(256),  dim3(256), 0, stream, ws);
  hipLaunchKernelGGL(k_passB,  dim3(256),  dim3(512), 0, stream, x, ws);
  hipLaunchKernelGGL(k_stats,  dim3(65),   dim3(256), 0, stream, ws);
  hipLaunchKernelGGL(k_layer1, dim3(256),  dim3(256), 0, stream, g1, bt1, Wenc, benc, ws);
  hipLaunchKernelGGL(k_red2,   dim3(1),    dim3(256), 0, stream, g2, bt2, ws);
  hipLaunchKernelGGL(k_layer2, dim3(256),  dim3(256), 0, stream, Wdec, bdec, ws);
  hipLaunchKernelGGL(k_red3,   dim3(1),    dim3(256), 0, stream, g3, bt3, ws);
  hipLaunchKernelGGL(k_out,    dim3(4096), dim3(256), 0, stream, bpi, bm, bth, out, ws);
}

// Round 2
// 475.307 us; speedup vs baseline: 1.0821x; 1.0821x over previous
//
#include <hip/hip_runtime.h>

#define BATCH 16384
#define DIM   4096

typedef __bf16 bf16x8 __attribute__((ext_vector_type(8)));
typedef float  f32x4  __attribute__((ext_vector_type(4)));
typedef unsigned short u16x8 __attribute__((ext_vector_type(8)));
typedef unsigned short u16x4 __attribute__((ext_vector_type(4)));

// ---- workspace layout (float offsets) ----
#define WS_ROWSUM 0         // 16384
#define WS_MED    16384     // 1
#define WS_NPART  16400     // 512*2
#define WS_SC3    17536     // 64
#define WS_CC3    17600     // 64
#define WS_A2PART 18432     // 256*64
#define WS_A3PART 34816     // 256*128
#define WS_CPART  67584     // 512*128 (per-block col sum[64] then sumsq[64])
#define WS_R      133120    // 16384*64 fp32
#define WS_A2     1181696   // 16384*32 fp32
#define WS_A3     1705984   // 16384*64 fp32
#define WS_WTIN   2754560   // 64*4096 bf16 (as ushort)
#define WS_WTO    2885632   // 3 * 4096*64 bf16

__device__ __forceinline__ unsigned short f2bf(float f){
  union { float f; unsigned u; } v; v.f = f;
  unsigned r = v.u + 0x7FFFu + ((v.u >> 16) & 1u);
  return (unsigned short)(r >> 16);
}

// L0: weight transpose/bf16 prep (blocks 0..1023) + row sums of x (blocks 1024..5119).
__global__ __launch_bounds__(256) void k_prep_rowsum(
    const float* __restrict__ x, const float* __restrict__ Win,
    const float* __restrict__ Wpi, const float* __restrict__ Wm,
    const float* __restrict__ Wth, float* __restrict__ ws){
  int b = blockIdx.x, t = threadIdx.x;
  if (b < 1024) {
    unsigned short* wtin = (unsigned short*)(ws + WS_WTIN);
    unsigned short* wto  = (unsigned short*)(ws + WS_WTO);
    int idx = (b * 256 + t) * 4;
    if (idx < 262144) {
      int k = idx >> 6, n = idx & 63;           // 4 consecutive n, same k
      float4 v = *(const float4*)(Win + idx);
      wtin[(n+0) * 4096 + k] = f2bf(v.x);
      wtin[(n+1) * 4096 + k] = f2bf(v.y);
      wtin[(n+2) * 4096 + k] = f2bf(v.z);
      wtin[(n+3) * 4096 + k] = f2bf(v.w);
    } else {
      int r = idx - 262144;
      int m = r >> 18, rr = r & 262143;
      int k = rr >> 12, n = rr & 4095;          // 4 consecutive n, same k
      const float* W = (m == 0) ? Wpi : ((m == 1) ? Wm : Wth);
      float4 v = *(const float4*)(W + rr);
      unsigned short* dst = wto + m * 262144 + n * 64 + k;
      dst[0] = f2bf(v.x); dst[64] = f2bf(v.y); dst[128] = f2bf(v.z); dst[192] = f2bf(v.w);
    }
  } else {
    int w = t >> 6, lane = t & 63;
    int row = (b - 1024) * 4 + w;
    const float4* xr = (const float4*)(x + (size_t)row * DIM);
    float s = 0.f;
    #pragma unroll
    for (int i = 0; i < 16; ++i) {
      float4 v = xr[lane + 64 * i];
      s += (v.x + v.y) + (v.z + v.w);
    }
    #pragma unroll
    for (int m = 32; m; m >>= 1) s += __shfl_xor(s, m);
    if (lane == 0) ws[WS_ROWSUM + row] = s;
  }
}

// L1: lower median of 16384 row sums via counting selection (float4 scan).
__global__ void k_median(float* __restrict__ ws){
  __shared__ int cls[4][64], ces[4][64];
  const float* rs = ws + WS_ROWSUM;
  int t = threadIdx.x, lane = t & 63, q = t >> 6;
  float cand = rs[blockIdx.x * 64 + lane];
  int cl = 0, ce = 0;
  const float4* base = (const float4*)(rs + q * 4096);
  #pragma unroll 4
  for (int i = 0; i < 1024; ++i) {
    float4 v = base[i];
    cl += (v.x < cand) + (v.y < cand) + (v.z < cand) + (v.w < cand);
    ce += (v.x == cand) + (v.y == cand) + (v.z == cand) + (v.w == cand);
  }
  cls[q][lane] = cl; ces[q][lane] = ce;
  __syncthreads();
  if (t < 64) {
    int C = cls[0][t] + cls[1][t] + cls[2][t] + cls[3][t];
    int E = ces[0][t] + ces[1][t] + ces[2][t] + ces[3][t];
    if (C <= 8191 && 8191 < C + E) ws[WS_MED] = cand;
  }
}

// L2: fused norm + R = norm @ W_in, with per-block column sum/sumsq of R and
// global sum/sumsq of norm. BM=32 rows, grid 512 (2 blocks/CU), 2-tile-ahead prefetch.
__global__ __launch_bounds__(512) void k_passB(const float* __restrict__ x, float* __restrict__ ws){
  __shared__ __align__(16) char Ab[2 * 4096];   // [2][32 rows][64 k] bf16, XOR-swizzled 16B chunks
  __shared__ __align__(16) char Bb[2 * 8192];   // [2][64 n   ][64 k] bf16, XOR-swizzled
  __shared__ float ainv_s[32];
  __shared__ float redn[8][2];
  __shared__ float cpart[2][64], cqpart[2][64];

  const unsigned short* wtin = (const unsigned short*)(ws + WS_WTIN);
  int tid = threadIdx.x;
  int r0 = blockIdx.x * 32;
  float med = ws[WS_MED];
  if (tid < 32) ainv_s[tid] = med / ws[WS_ROWSUM + r0 + tid];
  __syncthreads();

  int w = tid >> 6, lane = tid & 63;
  int li = lane & 15, u = lane >> 4;
  int wrb = (w & 1) * 16;       // wave A-row base
  int wc  = (w >> 1) * 16;      // wave B-col base

  int xrow = tid >> 4;                // 0..31
  int xcol0 = (tid & 15) * 4;         // 0..60
  int wn = tid >> 3, wkc = tid & 7;   // weight stage: row n, 16B chunk
  float ainv = ainv_s[xrow];

  f32x4 acc = (f32x4){0.f, 0.f, 0.f, 0.f};
  float nsum = 0.f, nsq = 0.f;
  float4 xa; u16x8 wv;

  auto LOADT = [&](int t){
    int coff = t * 64;
    xa = *(const float4*)(x + (size_t)(r0 + xrow) * DIM + coff + xcol0);
    wv = *(const u16x8*)(wtin + (size_t)wn * DIM + coff + wkc * 8);
  };
  auto WRITET = [&](int buf){
    float n0 = __logf(fmaf(xa.x, ainv, 1.f));
    float n1 = __logf(fmaf(xa.y, ainv, 1.f));
    float n2 = __logf(fmaf(xa.z, ainv, 1.f));
    float n3 = __logf(fmaf(xa.w, ainv, 1.f));
    nsum += (n0 + n1) + (n2 + n3);
    nsq  += (n0*n0 + n1*n1) + (n2*n2 + n3*n3);
    u16x4 p = { f2bf(n0), f2bf(n1), f2bf(n2), f2bf(n3) };
    int c = xcol0 >> 3, sub = (xcol0 >> 2) & 1;
    *(u16x4*)(Ab + buf * 4096 + xrow * 128 + ((c ^ (xrow & 7)) << 4) + sub * 8) = p;
    *(u16x8*)(Bb + buf * 8192 + wn * 128 + ((wkc ^ (wn & 7)) << 4)) = wv;
  };

  LOADT(0);
  WRITET(0);
  LOADT(1);
  __syncthreads();
  int cur = 0;
  int arow = wrb + li, brow = wc + li;
  for (int t = 0; t < 64; ++t) {
    const char* Au = Ab + cur * 4096;
    const char* Bu = Bb + cur * 8192;
    #pragma unroll
    for (int kk = 0; kk < 2; ++kk) {
      bf16x8 aF = *(const bf16x8*)(Au + arow * 128 + (((kk * 4 + u) ^ (arow & 7)) << 4));
      bf16x8 bF = *(const bf16x8*)(Bu + brow * 128 + (((kk * 4 + u) ^ (brow & 7)) << 4));
      // swapped operands: D[n][m] -> lane li = activation row, u*4+reg = weight col
      acc = __builtin_amdgcn_mfma_f32_16x16x32_bf16(bF, aF, acc, 0, 0, 0);
    }
    __syncthreads();
    if (t < 63) {
      WRITET(cur ^ 1);
      if (t < 62) LOADT(t + 2);
    }
    __syncthreads();
    cur ^= 1;
  }

  // store R: each lane one float4 (rows via li, 4 consecutive cols via u*4)
  float* R = ws + WS_R;
  *(f32x4*)(R + (size_t)(r0 + wrb + li) * 64 + wc + u * 4) = acc;

  // per-block column partial sums/sumsq from acc (reduce over 16 rows = li lanes)
  float s0 = acc[0], s1 = acc[1], s2 = acc[2], s3 = acc[3];
  float q0 = acc[0]*acc[0], q1 = acc[1]*acc[1], q2 = acc[2]*acc[2], q3 = acc[3]*acc[3];
  #pragma unroll
  for (int m = 1; m < 16; m <<= 1) {
    s0 += __shfl_xor(s0, m); s1 += __shfl_xor(s1, m);
    s2 += __shfl_xor(s2, m); s3 += __shfl_xor(s3, m);
    q0 += __shfl_xor(q0, m); q1 += __shfl_xor(q1, m);
    q2 += __shfl_xor(q2, m); q3 += __shfl_xor(q3, m);
  }
  if (li == 0) {
    int cb = wc + u * 4;
    cpart[w & 1][cb + 0] = s0; cpart[w & 1][cb + 1] = s1;
    cpart[w & 1][cb + 2] = s2; cpart[w & 1][cb + 3] = s3;
    cqpart[w & 1][cb + 0] = q0; cqpart[w & 1][cb + 1] = q1;
    cqpart[w & 1][cb + 2] = q2; cqpart[w & 1][cb + 3] = q3;
  }
  // norm stats
  #pragma unroll
  for (int m = 32; m; m >>= 1) { nsum += __shfl_xor(nsum, m); nsq += __shfl_xor(nsq, m); }
  if (lane == 0) { redn[w][0] = nsum; redn[w][1] = nsq; }
  __syncthreads();
  if (tid < 64) {
    ws[WS_CPART + blockIdx.x * 128 + tid]      = cpart[0][tid] + cpart[1][tid];
    ws[WS_CPART + blockIdx.x * 128 + 64 + tid] = cqpart[0][tid] + cqpart[1][tid];
  }
  if (tid == 0) {
    float S = 0.f, Q = 0.f;
    for (int i = 0; i < 8; ++i) { S += redn[i][0]; Q += redn[i][1]; }
    ws[WS_NPART + blockIdx.x * 2]     = S;
    ws[WS_NPART + blockIdx.x * 2 + 1] = Q;
  }
}

// L3: BN1 finalize (redundant per block) + h1 = relu(BN1(R)), a2 = h1 @ W_enc + b_enc,
// plus column partials of a2.
__global__ __launch_bounds__(256) void k_layer1(const float* __restrict__ g1, const float* __restrict__ bt1,
                         const float* __restrict__ Wenc, const float* __restrict__ benc,
                         float* __restrict__ ws){
  __shared__ float sc1[64], cc1[64];
  __shared__ float h1[64][65];
  __shared__ float we[64][33];
  __shared__ float sred[4][64], qred[4][64];
  __shared__ float sigred[4][2];
  __shared__ float sig2s;
  int t = threadIdx.x, lane = t & 63, w4 = t >> 6;

  // sig^2 of norm (unbiased) from 512 block partials
  {
    float s = 0.f, q = 0.f;
    for (int b = t; b < 512; b += 256) { s += ws[WS_NPART + b * 2]; q += ws[WS_NPART + b * 2 + 1]; }
    #pragma unroll
    for (int m = 32; m; m >>= 1) { s += __shfl_xor(s, m); q += __shfl_xor(q, m); }
    if (lane == 0) { sigred[w4][0] = s; sigred[w4][1] = q; }
  }
  // column partials of R
  {
    int col = t & 63, grp = t >> 6;
    float S = 0.f, Q = 0.f;
    for (int b = grp * 128; b < grp * 128 + 128; ++b) {
      S += ws[WS_CPART + b * 128 + col];
      Q += ws[WS_CPART + b * 128 + 64 + col];
    }
    sred[grp][col] = S; qred[grp][col] = Q;
  }
  for (int i = t; i < 2048; i += 256) we[i >> 5][i & 31] = Wenc[i];
  __syncthreads();
  if (t == 0) {
    double Sn = (double)sigred[0][0] + sigred[1][0] + sigred[2][0] + sigred[3][0];
    double Qn = (double)sigred[0][1] + sigred[1][1] + sigred[2][1] + sigred[3][1];
    double N = 67108864.0;
    sig2s = (float)((Qn - Sn * Sn / N) / (N - 1.0));
  }
  __syncthreads();
  if (t < 64) {
    float Sc = sred[0][t] + sred[1][t] + sred[2][t] + sred[3][t];
    float Qc = qred[0][t] + qred[1][t] + qred[2][t] + qred[3][t];
    float cm = Sc * (1.f / 16384.f);
    float cv = Qc * (1.f / 16384.f) - cm * cm;
    float sc = g1[t] * rsqrtf(cv + sig2s * 1e-5f);
    sc1[t] = sc; cc1[t] = bt1[t] - cm * sc;
  }
  __syncthreads();

  int r0 = blockIdx.x * 64;
  const float* R = ws + WS_R;
  for (int i = t; i < 4096; i += 256) {
    int row = i >> 6, col = i & 63;
    float v = fmaf(R[(size_t)(r0 + row) * 64 + col], sc1[col], cc1[col]);
    h1[row][col] = fmaxf(v, 0.f);
  }
  __syncthreads();
  int row = t & 63, cb = t >> 6;
  float a[8];
  #pragma unroll
  for (int j = 0; j < 8; ++j) a[j] = benc[cb * 8 + j];
  for (int k = 0; k < 64; ++k) {
    float hv = h1[row][k];
    #pragma unroll
    for (int j = 0; j < 8; ++j) a[j] = fmaf(hv, we[k][cb * 8 + j], a[j]);
  }
  float* A2 = ws + WS_A2;
  #pragma unroll
  for (int j = 0; j < 8; ++j) A2[(size_t)(r0 + row) * 32 + cb * 8 + j] = a[j];
  #pragma unroll
  for (int j = 0; j < 8; ++j) {
    float s = a[j], q = a[j] * a[j];
    #pragma unroll
    for (int m = 32; m; m >>= 1) { s += __shfl_xor(s, m); q += __shfl_xor(q, m); }
    if (lane == 0) {
      int c = cb * 8 + j;
      ws[WS_A2PART + blockIdx.x * 64 + c * 2]     = s;
      ws[WS_A2PART + blockIdx.x * 64 + c * 2 + 1] = q;
    }
  }
}

// L4: BN2 finalize (redundant) + h2 = relu(BN2(a2)), a3 = h2 @ W_dec + b_dec, a3 partials.
__global__ __launch_bounds__(256) void k_layer2(const float* __restrict__ g2, const float* __restrict__ bt2,
                         const float* __restrict__ Wdec, const float* __restrict__ bdec,
                         float* __restrict__ ws){
  __shared__ float h2[64][33];
  __shared__ float wd[32][65];
  __shared__ float sc2[32], cc2[32];
  __shared__ float sred2[8][32], qred2[8][32];
  int t = threadIdx.x, lane = t & 63;
  {
    int col = t & 31, grp = t >> 5;
    float S = 0.f, Q = 0.f;
    for (int b = grp * 32; b < grp * 32 + 32; ++b) {
      S += ws[WS_A2PART + b * 64 + col * 2];
      Q += ws[WS_A2PART + b * 64 + col * 2 + 1];
    }
    sred2[grp][col] = S; qred2[grp][col] = Q;
  }
  for (int i = t; i < 2048; i += 256) wd[i >> 6][i & 63] = Wdec[i];
  __syncthreads();
  if (t < 32) {
    float Sc = 0.f, Qc = 0.f;
    #pragma unroll
    for (int g = 0; g < 8; ++g) { Sc += sred2[g][t]; Qc += qred2[g][t]; }
    float cm = Sc * (1.f / 16384.f);
    float cv = Qc * (1.f / 16384.f) - cm * cm;
    float sc = g2[t] * rsqrtf(cv + 1e-5f);
    sc2[t] = sc; cc2[t] = bt2[t] - cm * sc;
  }
  __syncthreads();
  int r0 = blockIdx.x * 64;
  const float* A2 = ws + WS_A2;
  for (int i = t; i < 2048; i += 256) {
    int row = i >> 5, col = i & 31;
    float v = fmaf(A2[(size_t)(r0 + row) * 32 + col], sc2[col], cc2[col]);
    h2[row][col] = fmaxf(v, 0.f);
  }
  __syncthreads();
  int row = t & 63, cb = t >> 6;
  float a[16];
  #pragma unroll
  for (int j = 0; j < 16; ++j) a[j] = bdec[cb * 16 + j];
  for (int k = 0; k < 32; ++k) {
    float hv = h2[row][k];
    #pragma unroll
    for (int j = 0; j < 16; ++j) a[j] = fmaf(hv, wd[k][cb * 16 + j], a[j]);
  }
  float* A3 = ws + WS_A3;
  #pragma unroll
  for (int j = 0; j < 16; ++j) A3[(size_t)(r0 + row) * 64 + cb * 16 + j] = a[j];
  #pragma unroll
  for (int j = 0; j < 16; ++j) {
    float s = a[j], q = a[j] * a[j];
    #pragma unroll
    for (int m = 32; m; m >>= 1) { s += __shfl_xor(s, m); q += __shfl_xor(q, m); }
    if (lane == 0) {
      int c = cb * 16 + j;
      ws[WS_A3PART + blockIdx.x * 128 + c * 2]     = s;
      ws[WS_A3PART + blockIdx.x * 128 + c * 2 + 1] = q;
    }
  }
}

// L5: reduce a3 partials -> BN3 scale/shift.
__global__ void k_red3(const float* __restrict__ g3, const float* __restrict__ bt3, float* __restrict__ ws){
  __shared__ float red[128];
  int t = threadIdx.x;
  if (t < 128) {
    float s = 0.f;
    for (int b = 0; b < 256; ++b) s += ws[WS_A3PART + b * 128 + t];
    red[t] = s;
  }
  __syncthreads();
  if (t < 64) {
    float S = red[2 * t], Q = red[2 * t + 1];
    float cm = S * (1.f / 16384.f);
    float cv = Q * (1.f / 16384.f) - cm * cm;
    float sc = g3[t] * rsqrtf(cv + 1e-5f);
    ws[WS_SC3 + t] = sc; ws[WS_CC3 + t] = bt3[t] - cm * sc;
  }
}

// L6: heads. h3 = relu(BN3(a3)) in-register; out = act(h3 @ W + b).
// Swapped MFMA -> each lane holds 4 consecutive cols -> float4 nontemporal stores.
__global__ __launch_bounds__(256) void k_out(const float* __restrict__ bpi, const float* __restrict__ bm,
                      const float* __restrict__ bth, float* __restrict__ out,
                      float* __restrict__ ws){
  __shared__ __align__(16) char WB[256 * 128];   // [256 n][64 k] bf16, XOR-swizzled
  int t = threadIdx.x;
  int bx = blockIdx.x;
  int rb = bx >> 4, cb = bx & 15;
  int r0 = rb * 64, c0 = cb * 256;
  int w = t >> 6, lane = t & 63;
  int u = lane >> 4, li = lane & 15;

  const float* A3 = ws + WS_A3;
  const float* SC = ws + WS_SC3;
  const float* CC = ws + WS_CC3;
  int arow = r0 + w * 16 + li;
  const float4* a3p = (const float4*)(A3 + (size_t)arow * 64);
  bf16x8 aF[2];
  #pragma unroll
  for (int h = 0; h < 2; ++h) {
    float4 v0 = a3p[h * 8 + u * 2];
    float4 v1 = a3p[h * 8 + u * 2 + 1];
    int kb = h * 32 + u * 8;
    u16x8 uu;
    uu[0] = f2bf(fmaxf(fmaf(v0.x, SC[kb+0], CC[kb+0]), 0.f));
    uu[1] = f2bf(fmaxf(fmaf(v0.y, SC[kb+1], CC[kb+1]), 0.f));
    uu[2] = f2bf(fmaxf(fmaf(v0.z, SC[kb+2], CC[kb+2]), 0.f));
    uu[3] = f2bf(fmaxf(fmaf(v0.w, SC[kb+3], CC[kb+3]), 0.f));
    uu[4] = f2bf(fmaxf(fmaf(v1.x, SC[kb+4], CC[kb+4]), 0.f));
    uu[5] = f2bf(fmaxf(fmaf(v1.y, SC[kb+5], CC[kb+5]), 0.f));
    uu[6] = f2bf(fmaxf(fmaf(v1.z, SC[kb+6], CC[kb+6]), 0.f));
    uu[7] = f2bf(fmaxf(fmaf(v1.w, SC[kb+7], CC[kb+7]), 0.f));
    aF[h] = __builtin_bit_cast(bf16x8, uu);
  }

  const unsigned short* wto = (const unsigned short*)(ws + WS_WTO);
  for (int m = 0; m < 3; ++m) {
    __syncthreads();
    const unsigned short* src = wto + (size_t)m * 262144 + (size_t)c0 * 64;
    for (int ch = t; ch < 2048; ch += 256) {
      int n = ch >> 3, kc = ch & 7;
      u16x8 vchunk = *(const u16x8*)(src + n * 64 + kc * 8);
      *(u16x8*)(WB + n * 128 + ((kc ^ (n & 7)) << 4)) = vchunk;
    }
    __syncthreads();
    const float* bias = (m == 0) ? bpi : ((m == 1) ? bm : bth);
    float* po = out + (size_t)m * 67108864;
    for (int cg = 0; cg < 16; ++cg) {
      int n = cg * 16 + li;
      bf16x8 bF0 = *(const bf16x8*)(WB + n * 128 + (((0 + u) ^ (n & 7)) << 4));
      bf16x8 bF1 = *(const bf16x8*)(WB + n * 128 + (((4 + u) ^ (n & 7)) << 4));
      f32x4 d = (f32x4){0.f, 0.f, 0.f, 0.f};
      // swapped: row = arow (li), cols = c0 + cg*16 + u*4 + reg
      d = __builtin_amdgcn_mfma_f32_16x16x32_bf16(bF0, aF[0], d, 0, 0, 0);
      d = __builtin_amdgcn_mfma_f32_16x16x32_bf16(bF1, aF[1], d, 0, 0, 0);
      int colb = c0 + cg * 16 + u * 4;
      f32x4 bv = *(const f32x4*)(bias + colb);
      f32x4 z;
      #pragma unroll
      for (int r = 0; r < 4; ++r) {
        float zz = d[r] + bv[r];
        z[r] = (m == 0) ? (1.f / (1.f + __expf(-zz))) : __expf(zz);
      }
      __builtin_nontemporal_store(z, (f32x4*)(po + (size_t)arow * 4096 + colb));
    }
  }
}

extern "C" void kernel_launch(void* const* d_in, const int* in_sizes, int n_in,
                              void* d_out, int out_size, void* d_ws, size_t ws_size,
                              hipStream_t stream) {
  const float* x    = (const float*)d_in[0];
  const float* Win  = (const float*)d_in[1];
  // d_in[2] = b_in: cancels through BN1, unused.
  const float* g1   = (const float*)d_in[3];
  const float* bt1  = (const float*)d_in[4];
  const float* Wenc = (const float*)d_in[5];
  const float* benc = (const float*)d_in[6];
  const float* g2   = (const float*)d_in[7];
  const float* bt2  = (const float*)d_in[8];
  const float* Wdec = (const float*)d_in[9];
  const float* bdec = (const float*)d_in[10];
  const float* g3   = (const float*)d_in[11];
  const float* bt3  = (const float*)d_in[12];
  const float* Wpi  = (const float*)d_in[13];
  const float* bpi  = (const float*)d_in[14];
  const float* Wm   = (const float*)d_in[15];
  const float* bm   = (const float*)d_in[16];
  const float* Wth  = (const float*)d_in[17];
  const float* bth  = (const float*)d_in[18];
  float* ws  = (float*)d_ws;
  float* out = (float*)d_out;

  hipLaunchKernelGGL(k_prep_rowsum, dim3(5120), dim3(256), 0, stream, x, Win, Wpi, Wm, Wth, ws);
  hipLaunchKernelGGL(k_median,      dim3(256),  dim3(256), 0, stream, ws);
  hipLaunchKernelGGL(k_passB,       dim3(512),  dim3(512), 0, stream, x, ws);
  hipLaunchKernelGGL(k_layer1,      dim3(256),  dim3(256), 0, stream, g1, bt1, Wenc, benc, ws);
  hipLaunchKernelGGL(k_layer2,      dim3(256),  dim3(256), 0, stream, g2, bt2, Wdec, bdec, ws);
  hipLaunchKernelGGL(k_red3,        dim3(1),    dim3(256), 0, stream, g3, bt3, ws);
  hipLaunchKernelGGL(k_out,         dim3(4096), dim3(256), 0, stream, bpi, bm, bth, out, ws);
}